// Round 15
// baseline (334.068 us; speedup 1.0000x reference)
//
#include <hip/hip_runtime.h>
#include <hip/hip_fp16.h>
#include <cfloat>

#define BB 4
#define NN 4096
#define KK 16
#define NPTS (BB * NN)      // 16384

typedef __attribute__((ext_vector_type(8))) _Float16 f16x8;
typedef __attribute__((ext_vector_type(4))) float f32x4;
typedef unsigned int u32;
typedef unsigned long long u64;

__device__ __forceinline__ short f2h(float v) {
  __half h = __float2half_rn(v);
  return __half_as_short(h);
}
__device__ __forceinline__ u32 mulh2(u32 a, __half2 t) {
  __half2 x = __hmul2(*(__half2*)&a, t);
  return *(u32*)&x;
}

// ---------------- weights fp32 (o,(c,t),k) -> f16 permuted [o][(t,k,c)] padded ----------------
__device__ __forceinline__ void wcvt_body(const float* __restrict__ w2,
                                          short* __restrict__ wb,
                                          int CIN, int COUT, int CPAD, int LOGC,
                                          int total8, int i) {
  if (i >= total8) return;
  const int q8 = i * 8;
  const int QT = CPAD * 48;
  const int o = q8 / QT;
  const int r = q8 - o * QT;
  const int kq = r >> LOGC;
  const int c0 = r & (CPAD - 1);
  const int tt = kq >> 4;
  const int k = kq & 15;
  short h[8];
#pragma unroll
  for (int j = 0; j < 8; ++j) {
    const int c = c0 + j;
    const float v = (o < COUT && c < CIN) ? w2[(size_t)o * CIN * 48 + (c * 3 + tt) * 16 + k] : 0.0f;
    h[j] = f2h(v);
  }
  short* d = wb + (size_t)o * QT + r;
#pragma unroll
  for (int j = 0; j < 8; ++j) d[j] = h[j];
}

// ---------------- fused prep: pc2ft + xyzq + all 4 weight converts ----------------
__global__ __launch_bounds__(256) void prep_kernel(
    const float* __restrict__ pc, short* __restrict__ ft0, float4* __restrict__ xyzq,
    const float* __restrict__ w2_1, short* __restrict__ wb1,
    const float* __restrict__ w2_2, short* __restrict__ wb2,
    const float* __restrict__ w2_3, short* __restrict__ wb3,
    const float* __restrict__ w2_4, short* __restrict__ wb4) {
  const int blk = blockIdx.x;
  const int t = threadIdx.x;
  if (blk < 64) {
    const int i = blk * 256 + t;
    const float* s = pc + (size_t)i * 6;
    short* d = ft0 + (size_t)i * 8;
#pragma unroll
    for (int c = 0; c < 6; ++c) d[c] = f2h(s[c]);
    d[6] = 0; d[7] = 0;
    const float x = s[0], y = s[1], z = s[2];
    xyzq[i] = make_float4(x, y, z, fmaf(z, z, fmaf(y, y, x * x)));
  } else if (blk < 76) {
    wcvt_body(w2_1, wb1, 6, 32, 8, 3, 3072, (blk - 64) * 256 + t);
  } else if (blk < 124) {
    wcvt_body(w2_2, wb2, 32, 64, 32, 5, 12288, (blk - 76) * 256 + t);
  } else if (blk < 316) {
    wcvt_body(w2_3, wb3, 64, 128, 64, 6, 49152, (blk - 124) * 256 + t);
  } else {
    wcvt_body(w2_4, wb4, 128, 256, 128, 7, 196608, (blk - 316) * 256 + t);
  }
}

// ---------------- KNN: min-threshold select, TWO queries per block ----------------
__global__ __launch_bounds__(256) void knn_select2(const float4* __restrict__ xyzq,
                                                   int* __restrict__ idx_out) {
  __shared__ float wT[2][4];
  __shared__ u64 list[2][128];
  __shared__ int lcnt[2];
  const int g0 = blockIdx.x * 2;   // queries g0, g0+1 (same batch: NN is even)
  const int b = g0 >> 12;
  const int t = threadIdx.x;
  const int lane = t & 63;
  const float4* base = xyzq + (b << 12);
  const float4 qa = xyzq[g0];
  const float4 qb = xyzq[g0 + 1];
  float da[16], db[16];
  float mina = FLT_MAX, minb = FLT_MAX;
#pragma unroll
  for (int i = 0; i < 16; ++i) {
    const float4 c = base[i * 256 + t];
    const float dota = fmaf(qa.z, c.z, fmaf(qa.y, c.y, qa.x * c.x));
    da[i] = fmaf(-2.0f, dota, qa.w + c.w);
    mina = fminf(mina, da[i]);
    const float dotb = fmaf(qb.z, c.z, fmaf(qb.y, c.y, qb.x * c.x));
    db[i] = fmaf(-2.0f, dotb, qb.w + c.w);
    minb = fminf(minb, db[i]);
  }
  if (t < 2) lcnt[t] = 0;
  float va = mina, vb = minb;
#pragma unroll
  for (int k = 2; k <= 64; k <<= 1) {
#pragma unroll
    for (int j = k >> 1; j >= 1; j >>= 1) {
      const float oa = __shfl_xor(va, j, 64);
      const float ob = __shfl_xor(vb, j, 64);
      const bool take_min = (((lane & k) == 0) == ((lane & j) == 0));
      va = take_min ? fminf(va, oa) : fmaxf(va, oa);
      vb = take_min ? fminf(vb, ob) : fmaxf(vb, ob);
    }
  }
  const float twa = __shfl(va, 15, 64);
  const float twb = __shfl(vb, 15, 64);
  if (lane == 0) { wT[0][t >> 6] = twa; wT[1][t >> 6] = twb; }
  __syncthreads();
  const float Ta = fminf(fminf(wT[0][0], wT[0][1]), fminf(wT[0][2], wT[0][3]));
  const float Tb = fminf(fminf(wT[1][0], wT[1][1]), fminf(wT[1][2], wT[1][3]));
#pragma unroll
  for (int i = 0; i < 16; ++i) {
    if (da[i] <= Ta) {
      const u32 bits = __float_as_uint(da[i]);
      const u32 key = bits ^ ((u32)((int)bits >> 31) | 0x80000000u);
      const int pos = atomicAdd(&lcnt[0], 1);
      if (pos < 128) list[0][pos] = ((u64)key << 32) | (u32)(i * 256 + t);
    }
    if (db[i] <= Tb) {
      const u32 bits = __float_as_uint(db[i]);
      const u32 key = bits ^ ((u32)((int)bits >> 31) | 0x80000000u);
      const int pos = atomicAdd(&lcnt[1], 1);
      if (pos < 128) list[1][pos] = ((u64)key << 32) | (u32)(i * 256 + t);
    }
  }
  __syncthreads();
  if (t < 128) {
#pragma unroll
    for (int qq = 0; qq < 2; ++qq) {
      const int m = min(lcnt[qq], 128);
      const u64 my = (t < m) ? list[qq][t] : ~0ull;
      int rank = 0;
#pragma unroll 4
      for (int i = 0; i < m; ++i) rank += (list[qq][i] < my) ? 1 : 0;
      if (t < m && rank < 16)
        idx_out[(size_t)(g0 + qq) * KK + rank] = (int)(my & 0xFFFFFFFFull);
    }
  }
}

// ---------------- spider conv via f16 MFMA; A+B in LDS; tay computed INLINE ----------------
// Pipeline reorder vs R14: buildB(ph^1) moved AFTER the MFMA block, so the
// vmcnt wait for the o+1 gathers lands post-MFMA (~400 cyc more cover).
// OTILE=64 (L1-L3): wave = 64o x 16p. OTILE=128 (L4): k-split, wave = 64o x 64p
// x half-K; ks-pairs merge partial sums via end-of-kernel LDS reduction.
template <int CPAD, int LOGC, int COUT, int OTILE>
__global__ __launch_bounds__(256) void conv_mfma_kernel(
    const char* __restrict__ ftin,        // f16 [NPTS][CPAD]
    const short* __restrict__ wb,         // f16 [OPAD][QTOT] permuted
    const float* __restrict__ b2,
    const float4* __restrict__ xyzq,      // f32 [NPTS] (x,y,z,|.|^2)
    const float* __restrict__ w1,         // f32 [3][20] (this layer)
    const float* __restrict__ b1,         // f32 [3]
    const int* __restrict__ idx,
    float* __restrict__ pfout, int pfbstride,
    short* __restrict__ ftout, int CPADN) {
  constexpr int QTOT = CPAD * 48;
  constexpr int OUTER = QTOT / 64;
  constexpr int NJ = OTILE / 64;          // 1: base path, 2: k-split path
  constexpr int NJC = (NJ == 2) ? 4 : 1;  // B frags per wave
  constexpr int NH = OTILE / 32;          // dma calls per A buffer
  __shared__ __align__(16) short As[2][OTILE * 64];
  __shared__ __align__(16) short Bs[2][64 * 64];
  __shared__ __align__(16) unsigned short tayH[48 * 64];
  __shared__ int idxS[16 * 64];
  const int t = threadIdx.x;
  const int pbase = blockIdx.x * 64;
  const int obase = blockIdx.y * OTILE;
  const int b = pbase >> 12;
  const int nbase = pbase & (NN - 1);
  const int p_loc = t >> 2;
  const int sub = t & 3;
  // ---- neighbor byte-offsets + INLINE tay tile (4 k's per thread) ----
  {
    const int4 mi = *(const int4*)&idx[(size_t)(pbase + p_loc) * KK + sub * 4];
    const int gb = b << 12;
    idxS[(sub * 4 + 0) * 64 + p_loc] = (gb + mi.x) << (LOGC + 1);
    idxS[(sub * 4 + 1) * 64 + p_loc] = (gb + mi.y) << (LOGC + 1);
    idxS[(sub * 4 + 2) * 64 + p_loc] = (gb + mi.z) << (LOGC + 1);
    idxS[(sub * 4 + 3) * 64 + p_loc] = (gb + mi.w) << (LOGC + 1);
    const float4 self = xyzq[pbase + p_loc];
    const int nbr[4] = {gb + mi.x, gb + mi.y, gb + mi.z, gb + mi.w};
#pragma unroll
    for (int j = 0; j < 4; ++j) {
      const float4 nb = xyzq[nbr[j]];
      const float x = nb.x - self.x;
      const float y = nb.y - self.y;
      const float z = nb.z - self.z;
      float tb[20];
      tb[0] = 1.0f; tb[1] = x; tb[2] = y; tb[3] = z;
      tb[4] = x * x; tb[5] = x * y; tb[6] = x * z;
      tb[7] = y * y; tb[8] = y * z; tb[9] = z * z;
      tb[10] = tb[4] * x; tb[11] = tb[4] * y; tb[12] = tb[4] * z;
      tb[13] = tb[5] * y; tb[14] = tb[5] * z; tb[15] = tb[6] * z;
      tb[16] = tb[7] * y; tb[17] = tb[7] * z; tb[18] = tb[8] * z; tb[19] = tb[9] * z;
      const int k = sub * 4 + j;
#pragma unroll
      for (int c = 0; c < 3; ++c) {
        float s = b1[c];
#pragma unroll
        for (int jj = 0; jj < 20; ++jj) s = fmaf(w1[c * 20 + jj], tb[jj], s);
        tayH[(c * 16 + k) * 64 + p_loc] = (unsigned short)f2h(s);
      }
    }
  }
  // ---- A dma lane setup (source permutation implements the XOR swizzle) ----
  const int arow = t >> 3;                 // 0..31
  const int apos = t & 7;                  // stored chunk position
  const int aswz = (t >> 4) & 7;           // (row>>1)&7
  const short* awl[NH];
#pragma unroll
  for (int h = 0; h < NH; ++h)
    awl[h] = wb + (size_t)(obase + h * 32 + arow) * QTOT + ((apos ^ aswz) * 8);
  auto dmaA = [&](int o, int ph) {
#pragma unroll
    for (int h = 0; h < NH; ++h)
      __builtin_amdgcn_global_load_lds(
          (const __attribute__((address_space(1))) u32*)(awl[h] + o * 64),
          (__attribute__((address_space(3))) u32*)&As[ph][h * 2048 + t * 8], 16, 0, 0);
  };
  // ---- wave mapping ----
  const int lane = t & 63;
  const int w = t >> 6;
  const int wm = (NJ == 2) ? (w & 1) : 0;   // o-half
  const int ksw = (NJ == 2) ? (w >> 1) : 0; // k-half (NJ==2 only)
  const int wn = (NJ == 2) ? 0 : w;         // p-sixteenth (NJ==1 only)
  const int fr = lane & 15;
  const int fk = lane >> 4;
  const int rsw = (fr >> 1) & 7;           // frag-read un-swizzle
  const int bswz = (p_loc >> 1) & 7;       // build-write swizzle
  f32x4 acc[4][NJC];
#pragma unroll
  for (int i = 0; i < 4; ++i)
#pragma unroll
    for (int j = 0; j < NJC; ++j) acc[i][j] = (f32x4)(0.0f);

  uint4 fv[2];
  unsigned short tvh[2];
  auto prefB = [&](int o) {
#pragma unroll
    for (int z = 0; z < 2; ++z) {
      const int q0 = o * 64 + z * 32 + sub * 8;
      const int kq = q0 >> LOGC;
      const int c0 = q0 & (CPAD - 1);
      const int moff = idxS[(kq & 15) * 64 + p_loc];
      tvh[z] = tayH[kq * 64 + p_loc];
      fv[z] = *(const uint4*)(ftin + moff + (c0 << 1));
    }
  };
  auto buildB = [&](int ph) {
#pragma unroll
    for (int z = 0; z < 2; ++z) {
      const __half2 t2 = __half2half2(__ushort_as_half(tvh[z]));
      const uint4 f = fv[z];
      uint4 r;
      r.x = mulh2(f.x, t2); r.y = mulh2(f.y, t2);
      r.z = mulh2(f.z, t2); r.w = mulh2(f.w, t2);
      const int pos = (z * 4 + sub) ^ bswz;
      *(uint4*)&Bs[ph][p_loc * 64 + pos * 8] = r;
    }
  };
  // ---- prologue ----
  dmaA(0, 0);
  __syncthreads();            // tayH/idxS visible; dma0 drained
  prefB(0);
  buildB(0);
  __syncthreads();            // Bs[0] visible
#pragma unroll 1
  for (int o = 0; o < OUTER; ++o) {
    const int ph = o & 1;
    if (o + 1 < OUTER) { dmaA(o + 1, ph ^ 1); prefB(o + 1); }
    if constexpr (NJ == 2) {
      f16x8 af[4], bf[4];
      const int pos8 = ((ksw * 4 + fk) ^ rsw) * 8;
#pragma unroll
      for (int i = 0; i < 4; ++i)
        af[i] = *(const f16x8*)&As[ph][(wm * 64 + i * 16 + fr) * 64 + pos8];
#pragma unroll
      for (int j = 0; j < 4; ++j)
        bf[j] = *(const f16x8*)&Bs[ph][(j * 16 + fr) * 64 + pos8];
#pragma unroll
      for (int i = 0; i < 4; ++i)
#pragma unroll
        for (int j = 0; j < 4; ++j)
          acc[i][j] = __builtin_amdgcn_mfma_f32_16x16x32_f16(af[i], bf[j], acc[i][j], 0, 0, 0);
      if (o + 1 < OUTER) buildB(ph ^ 1);   // gather wait lands post-MFMA
    } else {
#pragma unroll
      for (int z = 0; z < 2; ++z) {
        f16x8 af[4], bf;
        const int pos8 = ((z * 4 + fk) ^ rsw) * 8;
#pragma unroll
        for (int i = 0; i < 4; ++i)
          af[i] = *(const f16x8*)&As[ph][(i * 16 + fr) * 64 + pos8];
        bf = *(const f16x8*)&Bs[ph][(wn * 16 + fr) * 64 + pos8];
#pragma unroll
        for (int i = 0; i < 4; ++i)
          acc[i][0] = __builtin_amdgcn_mfma_f32_16x16x32_f16(af[i], bf, acc[i][0], 0, 0, 0);
      }
      if (o + 1 < OUTER) buildB(ph ^ 1);   // gather wait lands post-MFMA
    }
    if (o + 1 < OUTER) __syncthreads();
  }
  // ---- k-split reduction (NJ==2): merge ks-pair partial sums via As scratch ----
  if constexpr (NJ == 2) {
    __syncthreads();
    float* red = (float*)(&As[0][0]) + wm * 4096;
    if (ksw == 1) {
#pragma unroll
      for (int i = 0; i < 4; ++i)
#pragma unroll
        for (int j = 0; j < 4; ++j)
#pragma unroll
          for (int r = 0; r < 4; ++r)
            red[((i * 4 + j) * 4 + r) * 64 + lane] = acc[i][j][r];
    }
    __syncthreads();
    if (ksw == 1) return;
#pragma unroll
    for (int i = 0; i < 4; ++i)
#pragma unroll
      for (int j = 0; j < 4; ++j)
#pragma unroll
        for (int r = 0; r < 4; ++r)
          acc[i][j][r] += red[((i * 4 + j) * 4 + r) * 64 + lane];
  }
  // ---- epilogue: bias + relu; fp32 -> pf, f16 -> ft_next ----
  float* outb = pfout + (size_t)b * pfbstride;
#pragma unroll
  for (int i = 0; i < 4; ++i) {
    const int o0 = obase + wm * 64 + i * 16 + fk * 4;
    if (o0 < COUT) {
      const float4 b4 = *(const float4*)&b2[o0];
#pragma unroll
      for (int j = 0; j < NJC; ++j) {
        const int p_l = (NJ == 2) ? (j * 16 + fr) : (wn * 16 + fr);
        const float v0 = fmaxf(acc[i][j][0] + b4.x, 0.0f);
        const float v1 = fmaxf(acc[i][j][1] + b4.y, 0.0f);
        const float v2 = fmaxf(acc[i][j][2] + b4.z, 0.0f);
        const float v3 = fmaxf(acc[i][j][3] + b4.w, 0.0f);
        outb[(size_t)(o0 + 0) * NN + nbase + p_l] = v0;
        outb[(size_t)(o0 + 1) * NN + nbase + p_l] = v1;
        outb[(size_t)(o0 + 2) * NN + nbase + p_l] = v2;
        outb[(size_t)(o0 + 3) * NN + nbase + p_l] = v3;
        if (ftout) {
          const __half2 h01 = __floats2half2_rn(v0, v1);
          const __half2 h23 = __floats2half2_rn(v2, v3);
          uint2 pk;
          pk.x = *(const u32*)&h01;
          pk.y = *(const u32*)&h23;
          *(uint2*)&ftout[(size_t)(pbase + p_l) * CPADN + o0] = pk;
        }
      }
    }
  }
}

// ---------------- top-2 over N per (b, channel) ----------------
__global__ __launch_bounds__(256) void top2_kernel(const float* __restrict__ pf,
                                                   float* __restrict__ cat) {
  const int row = blockIdx.x;  // b*480 + ch
  const float* p = pf + (size_t)row * NN;
  float m1 = -FLT_MAX, m2 = -FLT_MAX;
  for (int i = threadIdx.x; i < NN; i += 256) {
    const float v = p[i];
    if (v > m1) { m2 = m1; m1 = v; }
    else if (v > m2) m2 = v;
  }
#pragma unroll
  for (int off = 32; off > 0; off >>= 1) {
    const float o1 = __shfl_down(m1, off, 64);
    const float o2 = __shfl_down(m2, off, 64);
    const float nm1 = fmaxf(m1, o1);
    const float nm2 = fmaxf(fminf(m1, o1), fmaxf(m2, o2));
    m1 = nm1; m2 = nm2;
  }
  __shared__ float s1[4], s2[4];
  const int wid = threadIdx.x >> 6;
  if ((threadIdx.x & 63) == 0) { s1[wid] = m1; s2[wid] = m2; }
  __syncthreads();
  if (threadIdx.x == 0) {
    m1 = s1[0]; m2 = s2[0];
#pragma unroll
    for (int w = 1; w < 4; ++w) {
      const float o1 = s1[w], o2 = s2[w];
      const float nm1 = fmaxf(m1, o1);
      const float nm2 = fmaxf(fminf(m1, o1), fmaxf(m2, o2));
      m1 = nm1; m2 = nm2;
    }
    const int b = row / 480, ch = row % 480;
    cat[b * 960 + ch * 2 + 0] = m1;
    cat[b * 960 + ch * 2 + 1] = m2;
  }
}

extern "C" void kernel_launch(void* const* d_in, const int* in_sizes, int n_in,
                              void* d_out, int out_size, void* d_ws, size_t ws_size,
                              hipStream_t stream) {
  const float* pc = (const float*)d_in[0];
  const float* w1s[4]; const float* b1s[4]; const float* w2s[4]; const float* b2s[4];
  for (int l = 0; l < 4; ++l) {
    w1s[l] = (const float*)d_in[1 + 4 * l];
    b1s[l] = (const float*)d_in[2 + 4 * l];
    w2s[l] = (const float*)d_in[3 + 4 * l];
    b2s[l] = (const float*)d_in[4 + 4 * l];
  }
  // ---- workspace layout (bytes), fully disjoint (no aliasing) ----
  char* W = (char*)d_ws;
  int* idx = (int*)W;                                  // 1,048,576
  float4* xyzq = (float4*)(W + 1048576);               // 262,144 (live: prep -> L4 conv)
  short* wb1 = (short*)(W + 1310720);                  //    49,152
  short* wb2 = (short*)(W + 1359872);                  //   196,608
  short* wb3 = (short*)(W + 1556480);                  //   786,432
  short* wb4 = (short*)(W + 2342912);                  // 3,145,728
  short* ft0 = (short*)(W + 5488640);                  //   262,144
  short* ft1 = (short*)(W + 5750784);                  // 1,048,576
  short* ft2 = (short*)(W + 6799360);                  // 2,097,152
  short* ft3 = (short*)(W + 8896512);                  // 4,194,304  (end 13,090,816)
  float* cat = (float*)d_out;                          // B*960
  float* pf = (float*)d_out + BB * 960;                // (B, 480, N)
  const int pfstride = 480 * NN;

  prep_kernel<<<dim3(1084), 256, 0, stream>>>(
      pc, ft0, xyzq, w2s[0], wb1, w2s[1], wb2, w2s[2], wb3, w2s[3], wb4);
  knn_select2<<<dim3(NPTS / 2), 256, 0, stream>>>(xyzq, idx);
  conv_mfma_kernel<8, 3, 32, 64><<<dim3(NPTS / 64, 1), 256, 0, stream>>>(
      (const char*)ft0, wb1, b2s[0], xyzq, w1s[0], b1s[0], idx,
      pf + (size_t)0 * NN, pfstride, ft1, 32);
  conv_mfma_kernel<32, 5, 64, 64><<<dim3(NPTS / 64, 1), 256, 0, stream>>>(
      (const char*)ft1, wb2, b2s[1], xyzq, w1s[1], b1s[1], idx,
      pf + (size_t)32 * NN, pfstride, ft2, 64);
  conv_mfma_kernel<64, 6, 128, 64><<<dim3(NPTS / 64, 2), 256, 0, stream>>>(
      (const char*)ft2, wb3, b2s[2], xyzq, w1s[2], b1s[2], idx,
      pf + (size_t)96 * NN, pfstride, ft3, 128);
  conv_mfma_kernel<128, 7, 256, 128><<<dim3(NPTS / 64, 2), 256, 0, stream>>>(
      (const char*)ft3, wb4, b2s[3], xyzq, w1s[3], b1s[3], idx,
      pf + (size_t)224 * NN, pfstride, nullptr, 0);
  top2_kernel<<<dim3(BB * 480), 256, 0, stream>>>(pf, cat);
}